// Round 4
// baseline (127776.636 us; speedup 1.0000x reference)
//
#include <hip/hip_runtime.h>
#include <cstddef>
#include <cstdint>

#define B_  256
#define T_  512
#define D_  128
#define H_  256
#define G3_ 768
#define C_  10

__device__ __forceinline__ float sigmoid_f(float x) {
    return 1.0f / (1.0f + __expf(-x));
}
__device__ __forceinline__ float tanh_f(float x) {
    return 1.0f - 2.0f / (__expf(2.0f * x) + 1.0f);
}

// 3 uints hold the 6 bf16 weights (r,z,n for a k-pair) of one hidden unit j.
struct W2 { unsigned int a, b, c; };

__device__ __forceinline__ unsigned int bf16_rne(float f) {
    unsigned int u = __float_as_uint(f);
    return (u + 0x7fffu + ((u >> 16) & 1u)) >> 16;   // round-to-nearest-even
}

// ---------------------------------------------------------------------------
// Pack Whh[3H][H] fp32 -> Wp[k/2][j] = {r0|z0, n0|r1, z1|n1} bf16 pairs.
// w_gate(j,k) = Whh[gate*H + j][k]. 393 KB total (was 1 MB fp32).
// grid: 128 blocks (k-pairs) x 256 threads (j).
// ---------------------------------------------------------------------------
__global__ void k_pack_whh(const float* __restrict__ Whh, W2* __restrict__ Wp) {
    int j  = threadIdx.x;
    int k0 = blockIdx.x * 2;
    int k1 = k0 + 1;
    unsigned int r0 = bf16_rne(Whh[(size_t)(0 * H_ + j) * H_ + k0]);
    unsigned int z0 = bf16_rne(Whh[(size_t)(1 * H_ + j) * H_ + k0]);
    unsigned int n0 = bf16_rne(Whh[(size_t)(2 * H_ + j) * H_ + k0]);
    unsigned int r1 = bf16_rne(Whh[(size_t)(0 * H_ + j) * H_ + k1]);
    unsigned int z1 = bf16_rne(Whh[(size_t)(1 * H_ + j) * H_ + k1]);
    unsigned int n1 = bf16_rne(Whh[(size_t)(2 * H_ + j) * H_ + k1]);
    W2 w;
    w.a = (r0 << 16) | z0;
    w.b = (n0 << 16) | r1;
    w.c = (z1 << 16) | n1;
    Wp[(size_t)blockIdx.x * H_ + j] = w;
}

// ---------------------------------------------------------------------------
// C[M,N] = A[M,K] @ W[N,K]^T + bias[N]  (fp32 NT, chunk-major A rows).
// ---------------------------------------------------------------------------
__global__ __launch_bounds__(256, 2) void k_gemm_nt_bias(
    const float* __restrict__ A, long Abstride,
    const float* __restrict__ W,
    const float* __restrict__ bias, float* __restrict__ C,
    int N, int K, int tcShift)
{
    __shared__ float As[16][128];
    __shared__ float Ws[16][64];
    const int tid = threadIdx.x;
    const int tx = tid & 15;
    const int ty = tid >> 4;
    const int m0 = blockIdx.y * 128;
    const int n0 = blockIdx.x * 64;
    const int arow = tid >> 1;
    const int ak   = (tid & 1) * 8;
    const int wrow = tid >> 2;
    const int wk   = (tid & 3) * 4;

    const int mask = (1 << tcShift) - 1;
    const int mg = m0 + arow;
    const float* Arow = A + (size_t)(mg >> tcShift) * Abstride + (size_t)(mg & mask) * K;
    const float* Wrow = W + (size_t)(n0 + wrow) * K;

    float acc[8][4] = {};

    for (int k0 = 0; k0 < K; k0 += 16) {
        float4 a0 = *(const float4*)&Arow[k0 + ak];
        float4 a1 = *(const float4*)&Arow[k0 + ak + 4];
        float4 wv = *(const float4*)&Wrow[k0 + wk];
        __syncthreads();
        As[ak + 0][arow] = a0.x; As[ak + 1][arow] = a0.y;
        As[ak + 2][arow] = a0.z; As[ak + 3][arow] = a0.w;
        As[ak + 4][arow] = a1.x; As[ak + 5][arow] = a1.y;
        As[ak + 6][arow] = a1.z; As[ak + 7][arow] = a1.w;
        Ws[wk + 0][wrow] = wv.x; Ws[wk + 1][wrow] = wv.y;
        Ws[wk + 2][wrow] = wv.z; Ws[wk + 3][wrow] = wv.w;
        __syncthreads();
#pragma unroll
        for (int kk = 0; kk < 16; kk++) {
            float a8[8], b4[4];
            *(float4*)&a8[0] = *(const float4*)&As[kk][ty * 8];
            *(float4*)&a8[4] = *(const float4*)&As[kk][ty * 8 + 4];
            *(float4*)&b4[0] = *(const float4*)&Ws[kk][tx * 4];
#pragma unroll
            for (int ii = 0; ii < 8; ii++)
#pragma unroll
                for (int jj = 0; jj < 4; jj++)
                    acc[ii][jj] = fmaf(a8[ii], b4[jj], acc[ii][jj]);
        }
    }

    float b4[4];
#pragma unroll
    for (int jj = 0; jj < 4; jj++) b4[jj] = bias[n0 + tx * 4 + jj];
#pragma unroll
    for (int ii = 0; ii < 8; ii++) {
        float4 v;
        v.x = acc[ii][0] + b4[0];
        v.y = acc[ii][1] + b4[1];
        v.z = acc[ii][2] + b4[2];
        v.w = acc[ii][3] + b4[3];
        *(float4*)&C[(size_t)(m0 + ty * 8 + ii) * N + n0 + tx * 4] = v;
    }
}

// ---------------------------------------------------------------------------
// GRU scan, bf16 weights / fp32 state. 128 blocks x 256 thr; block owns 2
// batch rows; h double-buffered in LDS; weights streamed from L2 (393 KB/CU/
// step, register-double-buffered); gi for t+1 prefetched during step t.
// ---------------------------------------------------------------------------
__global__ __launch_bounds__(256, 1) void k_gru_scan_chunk(
    const float* __restrict__ gi,      // [B*Tc][3H] chunk-major (bih added)
    const W2* __restrict__ Wp,         // [128][256] packed bf16 weights
    const float* __restrict__ bhh,     // [768]
    float* __restrict__ h_state,       // [B][H] in/out
    float* __restrict__ out_seq,       // [B*Tc][H] or nullptr
    int Tc, int initZero)
{
    __shared__ __align__(16) float hbuf[2][2][H_];
    const int j  = threadIdx.x;
    const int b0 = blockIdx.x * 2;

    const float br = bhh[j];
    const float bz = bhh[H_ + j];
    const float bn = bhh[2 * H_ + j];

    float hprev[2];
#pragma unroll
    for (int bb = 0; bb < 2; bb++) {
        hprev[bb] = initZero ? 0.0f : h_state[(size_t)(b0 + bb) * H_ + j];
        hbuf[0][bb][j] = hprev[bb];
    }
    __syncthreads();

    // preload gi for t=0
    float g[2][3];
#pragma unroll
    for (int bb = 0; bb < 2; bb++) {
        const float* gp = gi + (size_t)(b0 + bb) * Tc * G3_;
        g[bb][0] = gp[j];
        g[bb][1] = gp[H_ + j];
        g[bb][2] = gp[2 * H_ + j];
    }

    int cur = 0;
    for (int t = 0; t < Tc; ++t) {
        // prefetch next step's gi (hides ~900cyc HBM latency under the k-loop)
        float gnext[2][3];
        if (t + 1 < Tc) {
#pragma unroll
            for (int bb = 0; bb < 2; bb++) {
                const float* gp = gi + ((size_t)(b0 + bb) * Tc + t + 1) * G3_;
                gnext[bb][0] = gp[j];
                gnext[bb][1] = gp[H_ + j];
                gnext[bb][2] = gp[2 * H_ + j];
            }
        }

        float ar[2] = {}, az[2] = {}, an[2] = {};

        // register-double-buffered weight stream: 4 W2 rows = 8 k's per stage
        W2 wb[2][4];
        const W2* wrow = Wp + j;
#pragma unroll
        for (int r = 0; r < 4; r++) wb[0][r] = wrow[(size_t)r * H_];

        for (int k0 = 0; k0 < H_; k0 += 8) {
            const int pb = (k0 >> 3) & 1;
            if (k0 + 8 < H_) {
#pragma unroll
                for (int r = 0; r < 4; r++)
                    wb[pb ^ 1][r] = wrow[(size_t)(k0 / 2 + 4 + r) * H_];
            }
            float ha[2][8];
#pragma unroll
            for (int bb = 0; bb < 2; bb++) {
                *(float4*)&ha[bb][0] = *(const float4*)&hbuf[cur][bb][k0];
                *(float4*)&ha[bb][4] = *(const float4*)&hbuf[cur][bb][k0 + 4];
            }
#pragma unroll
            for (int r = 0; r < 4; r++) {          // W2 r covers k0+2r, k0+2r+1
                const W2 w = wb[pb][r];
                const float wr0 = __uint_as_float(w.a & 0xffff0000u);
                const float wz0 = __uint_as_float(w.a << 16);
                const float wn0 = __uint_as_float(w.b & 0xffff0000u);
                const float wr1 = __uint_as_float(w.b << 16);
                const float wz1 = __uint_as_float(w.c & 0xffff0000u);
                const float wn1 = __uint_as_float(w.c << 16);
#pragma unroll
                for (int bb = 0; bb < 2; bb++) {
                    const float h0 = ha[bb][2 * r];
                    const float h1 = ha[bb][2 * r + 1];
                    ar[bb] = fmaf(wr0, h0, ar[bb]);
                    az[bb] = fmaf(wz0, h0, az[bb]);
                    an[bb] = fmaf(wn0, h0, an[bb]);
                    ar[bb] = fmaf(wr1, h1, ar[bb]);
                    az[bb] = fmaf(wz1, h1, az[bb]);
                    an[bb] = fmaf(wn1, h1, an[bb]);
                }
            }
        }

        float hn[2];
#pragma unroll
        for (int bb = 0; bb < 2; bb++) {
            float r   = sigmoid_f(g[bb][0] + ar[bb] + br);
            float z   = sigmoid_f(g[bb][1] + az[bb] + bz);
            float ghn = an[bb] + bn;               // bhh_n inside the r-gate
            float n   = tanh_f(g[bb][2] + r * ghn);
            hn[bb] = (1.0f - z) * n + z * hprev[bb];
        }

#pragma unroll
        for (int bb = 0; bb < 2; bb++) {
            hbuf[cur ^ 1][bb][j] = hn[bb];
            hprev[bb] = hn[bb];
        }

        if (out_seq) {
#pragma unroll
            for (int bb = 0; bb < 2; bb++)
                out_seq[((size_t)(b0 + bb) * Tc + t) * H_ + j] = hn[bb];
        }
        if (t == Tc - 1) {
#pragma unroll
            for (int bb = 0; bb < 2; bb++)
                h_state[(size_t)(b0 + bb) * H_ + j] = hn[bb];
        }

#pragma unroll
        for (int bb = 0; bb < 2; bb++) {
            g[bb][0] = gnext[bb][0];
            g[bb][1] = gnext[bb][1];
            g[bb][2] = gnext[bb][2];
        }
        __syncthreads();
        cur ^= 1;
    }
}

// ---------------------------------------------------------------------------
__global__ void k_fc(const float* __restrict__ h, const float* __restrict__ Wfc,
                     const float* __restrict__ bfc, float* __restrict__ out)
{
    int idx = blockIdx.x * blockDim.x + threadIdx.x;
    if (idx >= B_ * C_) return;
    int b = idx / C_, c = idx % C_;
    const float* hp = h + (size_t)b * H_;
    const float* wp = Wfc + (size_t)c * H_;
    float s = bfc[c];
#pragma unroll 4
    for (int k = 0; k < H_; k++) s = fmaf(hp[k], wp[k], s);
    out[idx] = s;
}

// ---------------------------------------------------------------------------
extern "C" void kernel_launch(void* const* d_in, const int* in_sizes, int n_in,
                              void* d_out, int out_size, void* d_ws, size_t ws_size,
                              hipStream_t stream)
{
    const float* x    = (const float*)d_in[0];
    const float* Wih0 = (const float*)d_in[1];
    const float* Whh0 = (const float*)d_in[2];
    const float* bih0 = (const float*)d_in[3];
    const float* bhh0 = (const float*)d_in[4];
    const float* Wih1 = (const float*)d_in[5];
    const float* Whh1 = (const float*)d_in[6];
    const float* bih1 = (const float*)d_in[7];
    const float* bhh1 = (const float*)d_in[8];
    const float* Wfc  = (const float*)d_in[9];
    const float* bfc  = (const float*)d_in[10];
    float* out = (float*)d_out;

    // ---- pick the largest power-of-two T-chunk that fits ws_size ----------
    const size_t fixedB = 2 * (size_t)(H_ / 2) * H_ * sizeof(W2)  // wp0, wp1
                        + 2 * (size_t)B_ * H_ * 4                 // h_state x2
                        + 4096;
    int Tc = 128, tcShift = 7;
    while (Tc > 1) {
        size_t need = fixedB
                    + 2 * (size_t)B_ * Tc * G3_ * 4    // gi0, gi1 chunks
                    + (size_t)B_ * Tc * H_ * 4;        // h1 chunk
        if (need <= ws_size) break;
        Tc >>= 1; tcShift--;
    }
    const int nChunks = T_ / Tc;

    char* ws = (char*)d_ws;
    size_t off = 0;
    auto alloc = [&](size_t bytes) { char* p = ws + off; off += (bytes + 255) & ~(size_t)255; return p; };
    float* gi0  = (float*)alloc((size_t)B_ * Tc * G3_ * 4);
    float* gi1  = (float*)alloc((size_t)B_ * Tc * G3_ * 4);
    float* h1c  = (float*)alloc((size_t)B_ * Tc * H_ * 4);
    W2*    wp0  = (W2*)alloc((size_t)(H_ / 2) * H_ * sizeof(W2));
    W2*    wp1  = (W2*)alloc((size_t)(H_ / 2) * H_ * sizeof(W2));
    float* hst0 = (float*)alloc((size_t)B_ * H_ * 4);
    float* hst1 = (float*)alloc((size_t)B_ * H_ * 4);

    k_pack_whh<<<H_ / 2, 256, 0, stream>>>(Whh0, wp0);
    k_pack_whh<<<H_ / 2, 256, 0, stream>>>(Whh1, wp1);

    const dim3 ggrid(G3_ / 64, (B_ * Tc) / 128);

    for (int c = 0; c < nChunks; ++c) {
        k_gemm_nt_bias<<<ggrid, 256, 0, stream>>>(
            x + (size_t)c * Tc * D_, (long)T_ * D_, Wih0, bih0, gi0,
            G3_, D_, tcShift);
        k_gru_scan_chunk<<<B_ / 2, 256, 0, stream>>>(
            gi0, wp0, bhh0, hst0, h1c, Tc, c == 0);
        k_gemm_nt_bias<<<ggrid, 256, 0, stream>>>(
            h1c, (long)Tc * H_, Wih1, bih1, gi1,
            G3_, H_, tcShift);
        k_gru_scan_chunk<<<B_ / 2, 256, 0, stream>>>(
            gi1, wp1, bhh1, hst1, nullptr, Tc, c == 0);
    }

    k_fc<<<10, 256, 0, stream>>>(hst1, Wfc, bfc, out);
}

// Round 5
// 42275.046 us; speedup vs baseline: 3.0225x; 3.0225x over previous
//
#include <hip/hip_runtime.h>
#include <cstddef>
#include <cstdint>

#define B_  256
#define T_  512
#define D_  128
#define H_  256
#define G3_ 768
#define C_  10

__device__ __forceinline__ float sigmoid_f(float x) {
    return 1.0f / (1.0f + __expf(-x));
}
__device__ __forceinline__ float tanh_f(float x) {
    return 1.0f - 2.0f / (__expf(2.0f * x) + 1.0f);
}

__device__ __forceinline__ unsigned int bf16_rne(float f) {
    unsigned int u = __float_as_uint(f);
    return (u + 0x7fffu + ((u >> 16) & 1u)) >> 16;   // round-to-nearest-even
}
__device__ __forceinline__ unsigned int pack2(float even, float odd) {
    return bf16_rne(even) | (bf16_rne(odd) << 16);   // even->lo16, odd->hi16
}
#define UNPK_EVEN(x) __uint_as_float((x) << 16)
#define UNPK_ODD(x)  __uint_as_float((x) & 0xffff0000u)

// ---------------------------------------------------------------------------
// Pack Whh[3H][H] fp32 -> per-lane-resident bf16 layout.
// Scan thread t (of 512) owns j = (t>>6)*32 + (t&31), k-half q = (t>>5)&1.
// Wl[(g*16+i4)*512 + t] = uint4 of 4 packed k-pairs: k = q*128 + 8*i4 + 0..7.
// grid: 48 blocks (g*16+i4) x 512 threads.
// ---------------------------------------------------------------------------
__global__ void k_pack_whh(const float* __restrict__ Whh, uint4* __restrict__ Wl) {
    const int g  = blockIdx.x >> 4;
    const int i4 = blockIdx.x & 15;
    const int t  = threadIdx.x;
    const int j  = (t >> 6) * 32 + (t & 31);
    const int q  = (t >> 5) & 1;
    const int kb = q * 128 + 8 * i4;
    const float* row = Whh + (size_t)(g * H_ + j) * H_;
    uint4 u;
    u.x = pack2(row[kb + 0], row[kb + 1]);
    u.y = pack2(row[kb + 2], row[kb + 3]);
    u.z = pack2(row[kb + 4], row[kb + 5]);
    u.w = pack2(row[kb + 6], row[kb + 7]);
    Wl[(size_t)blockIdx.x * 512 + t] = u;
}

// ---------------------------------------------------------------------------
// C[M,N] = A[M,K] @ W[N,K]^T + bias[N]  (fp32 NT, chunk-major A rows).
// ---------------------------------------------------------------------------
__global__ __launch_bounds__(256, 2) void k_gemm_nt_bias(
    const float* __restrict__ A, long Abstride,
    const float* __restrict__ W,
    const float* __restrict__ bias, float* __restrict__ C,
    int N, int K, int tcShift)
{
    __shared__ float As[16][128];
    __shared__ float Ws[16][64];
    const int tid = threadIdx.x;
    const int tx = tid & 15;
    const int ty = tid >> 4;
    const int m0 = blockIdx.y * 128;
    const int n0 = blockIdx.x * 64;
    const int arow = tid >> 1;
    const int ak   = (tid & 1) * 8;
    const int wrow = tid >> 2;
    const int wk   = (tid & 3) * 4;

    const int mask = (1 << tcShift) - 1;
    const int mg = m0 + arow;
    const float* Arow = A + (size_t)(mg >> tcShift) * Abstride + (size_t)(mg & mask) * K;
    const float* Wrow = W + (size_t)(n0 + wrow) * K;

    float acc[8][4] = {};

    for (int k0 = 0; k0 < K; k0 += 16) {
        float4 a0 = *(const float4*)&Arow[k0 + ak];
        float4 a1 = *(const float4*)&Arow[k0 + ak + 4];
        float4 wv = *(const float4*)&Wrow[k0 + wk];
        __syncthreads();
        As[ak + 0][arow] = a0.x; As[ak + 1][arow] = a0.y;
        As[ak + 2][arow] = a0.z; As[ak + 3][arow] = a0.w;
        As[ak + 4][arow] = a1.x; As[ak + 5][arow] = a1.y;
        As[ak + 6][arow] = a1.z; As[ak + 7][arow] = a1.w;
        Ws[wk + 0][wrow] = wv.x; Ws[wk + 1][wrow] = wv.y;
        Ws[wk + 2][wrow] = wv.z; Ws[wk + 3][wrow] = wv.w;
        __syncthreads();
#pragma unroll
        for (int kk = 0; kk < 16; kk++) {
            float a8[8], b4[4];
            *(float4*)&a8[0] = *(const float4*)&As[kk][ty * 8];
            *(float4*)&a8[4] = *(const float4*)&As[kk][ty * 8 + 4];
            *(float4*)&b4[0] = *(const float4*)&Ws[kk][tx * 4];
#pragma unroll
            for (int ii = 0; ii < 8; ii++)
#pragma unroll
                for (int jj = 0; jj < 4; jj++)
                    acc[ii][jj] = fmaf(a8[ii], b4[jj], acc[ii][jj]);
        }
    }

    float b4[4];
#pragma unroll
    for (int jj = 0; jj < 4; jj++) b4[jj] = bias[n0 + tx * 4 + jj];
#pragma unroll
    for (int ii = 0; ii < 8; ii++) {
        float4 v;
        v.x = acc[ii][0] + b4[0];
        v.y = acc[ii][1] + b4[1];
        v.z = acc[ii][2] + b4[2];
        v.w = acc[ii][3] + b4[3];
        *(float4*)&C[(size_t)(m0 + ty * 8 + ii) * N + n0 + tx * 4] = v;
    }
}

// ---------------------------------------------------------------------------
// VGPR-resident GRU scan. 256 blocks (1 batch row each) x 512 thr (8 waves,
// 2/SIMD). Lane owns hidden unit j and k-half q: its 192 bf16 Whh weights
// live in 48 uint4 REGISTERS for the whole dispatch (zero weight traffic per
// step). h[256] double-buffered in LDS (broadcast reads, 1 barrier/step);
// k-half partials combined with one __shfl_xor. All register-array indices
// are compile-time constants (R4 lesson: runtime indices -> scratch spill).
// ---------------------------------------------------------------------------
__device__ __forceinline__ void dot8(float2& acc, uint4 u, float4 hA, float4 hB) {
    acc.x = fmaf(UNPK_EVEN(u.x), hA.x, acc.x);
    acc.y = fmaf(UNPK_ODD(u.x),  hA.y, acc.y);
    acc.x = fmaf(UNPK_EVEN(u.y), hA.z, acc.x);
    acc.y = fmaf(UNPK_ODD(u.y),  hA.w, acc.y);
    acc.x = fmaf(UNPK_EVEN(u.z), hB.x, acc.x);
    acc.y = fmaf(UNPK_ODD(u.z),  hB.y, acc.y);
    acc.x = fmaf(UNPK_EVEN(u.w), hB.z, acc.x);
    acc.y = fmaf(UNPK_ODD(u.w),  hB.w, acc.y);
}

__global__ __launch_bounds__(512, 2) void k_gru_scan_resident(
    const float* __restrict__ gi,      // [B*Tc][3H] chunk-major (bih added)
    const uint4* __restrict__ Wl,      // [48][512] packed per-lane weights
    const float* __restrict__ bhh,     // [768]
    float* __restrict__ h_state,       // [B][H] in/out
    float* __restrict__ out_seq,       // [B*Tc][H] or nullptr
    int Tc, int initZero)
{
    __shared__ __align__(16) float hbuf[2][H_];
    const int t512 = threadIdx.x;
    const int j    = (t512 >> 6) * 32 + (t512 & 31);
    const int q    = (t512 >> 5) & 1;
    const int kb   = q * 128;
    const int b    = blockIdx.x;

    // ---- load resident weights (once per dispatch, coalesced dwordx4) ----
    uint4 wq[48];
    {
        const uint4* wl = Wl + t512;
#pragma unroll
        for (int r = 0; r < 48; r++) wq[r] = wl[(size_t)r * 512];
    }

    const float br = bhh[j];
    const float bz = bhh[H_ + j];
    const float bn = bhh[2 * H_ + j];

    hbuf[0][j] = initZero ? 0.0f : h_state[(size_t)b * H_ + j];  // dup writes ok
    __syncthreads();

    const float* gbase = gi + (size_t)b * Tc * G3_;

    int cur = 0;
    for (int t = 0; t < Tc; ++t) {
        const float* grow = gbase + (size_t)t * G3_;
        float gr = grow[j];
        float gz = grow[H_ + j];
        float gn = grow[2 * H_ + j];
        float hp = hbuf[cur][j];

        float2 accr = {0.f, 0.f}, accz = {0.f, 0.f}, accn = {0.f, 0.f};
#pragma unroll
        for (int i4 = 0; i4 < 16; i4++) {
            float4 hA = *(const float4*)&hbuf[cur][kb + 8 * i4];
            float4 hB = *(const float4*)&hbuf[cur][kb + 8 * i4 + 4];
            dot8(accr, wq[0 * 16 + i4], hA, hB);
            dot8(accz, wq[1 * 16 + i4], hA, hB);
            dot8(accn, wq[2 * 16 + i4], hA, hB);
        }
        float ar = accr.x + accr.y;
        float az = accz.x + accz.y;
        float an = accn.x + accn.y;
        ar += __shfl_xor(ar, 32, 64);   // combine the two k-halves
        az += __shfl_xor(az, 32, 64);
        an += __shfl_xor(an, 32, 64);

        float r  = sigmoid_f(gr + ar + br);
        float z  = sigmoid_f(gz + az + bz);
        float n  = tanh_f(gn + r * (an + bn));   // bhh_n inside the r-gate
        float hn = (1.0f - z) * n + z * hp;

        if ((t512 & 63) < 32) {          // q==0 lanes publish
            hbuf[cur ^ 1][j] = hn;
            if (out_seq)
                out_seq[((size_t)b * Tc + t) * H_ + j] = hn;
            if (t == Tc - 1)
                h_state[(size_t)b * H_ + j] = hn;
        }
        __syncthreads();
        cur ^= 1;
    }
}

// ---------------------------------------------------------------------------
__global__ void k_fc(const float* __restrict__ h, const float* __restrict__ Wfc,
                     const float* __restrict__ bfc, float* __restrict__ out)
{
    int idx = blockIdx.x * blockDim.x + threadIdx.x;
    if (idx >= B_ * C_) return;
    int b = idx / C_, c = idx % C_;
    const float* hp = h + (size_t)b * H_;
    const float* wp = Wfc + (size_t)c * H_;
    float s = bfc[c];
#pragma unroll 4
    for (int k = 0; k < H_; k++) s = fmaf(hp[k], wp[k], s);
    out[idx] = s;
}

// ---------------------------------------------------------------------------
extern "C" void kernel_launch(void* const* d_in, const int* in_sizes, int n_in,
                              void* d_out, int out_size, void* d_ws, size_t ws_size,
                              hipStream_t stream)
{
    const float* x    = (const float*)d_in[0];
    const float* Wih0 = (const float*)d_in[1];
    const float* Whh0 = (const float*)d_in[2];
    const float* bih0 = (const float*)d_in[3];
    const float* bhh0 = (const float*)d_in[4];
    const float* Wih1 = (const float*)d_in[5];
    const float* Whh1 = (const float*)d_in[6];
    const float* bih1 = (const float*)d_in[7];
    const float* bhh1 = (const float*)d_in[8];
    const float* Wfc  = (const float*)d_in[9];
    const float* bfc  = (const float*)d_in[10];
    float* out = (float*)d_out;

    const size_t wlBytes = (size_t)48 * 512 * sizeof(uint4);   // 393,216 B

    // ---- pick the largest power-of-two T-chunk that fits ws_size ----------
    const size_t fixedB = 2 * wlBytes
                        + 2 * (size_t)B_ * H_ * 4
                        + 8192;
    int Tc = 128, tcShift = 7;
    while (Tc > 1) {
        size_t need = fixedB
                    + 2 * (size_t)B_ * Tc * G3_ * 4    // gi0, gi1 chunks
                    + (size_t)B_ * Tc * H_ * 4;        // h1 chunk
        if (need <= ws_size) break;
        Tc >>= 1; tcShift--;
    }
    const int nChunks = T_ / Tc;

    char* ws = (char*)d_ws;
    size_t off = 0;
    auto alloc = [&](size_t bytes) { char* p = ws + off; off += (bytes + 255) & ~(size_t)255; return p; };
    float* gi0  = (float*)alloc((size_t)B_ * Tc * G3_ * 4);
    float* gi1  = (float*)alloc((size_t)B_ * Tc * G3_ * 4);
    float* h1c  = (float*)alloc((size_t)B_ * Tc * H_ * 4);
    uint4* wl0  = (uint4*)alloc(wlBytes);
    uint4* wl1  = (uint4*)alloc(wlBytes);
    float* hst0 = (float*)alloc((size_t)B_ * H_ * 4);
    float* hst1 = (float*)alloc((size_t)B_ * H_ * 4);

    k_pack_whh<<<48, 512, 0, stream>>>(Whh0, wl0);
    k_pack_whh<<<48, 512, 0, stream>>>(Whh1, wl1);

    const dim3 ggrid(G3_ / 64, (B_ * Tc) / 128);

    for (int c = 0; c < nChunks; ++c) {
        k_gemm_nt_bias<<<ggrid, 256, 0, stream>>>(
            x + (size_t)c * Tc * D_, (long)T_ * D_, Wih0, bih0, gi0,
            G3_, D_, tcShift);
        k_gru_scan_resident<<<B_, 512, 0, stream>>>(
            gi0, wl0, bhh0, hst0, h1c, Tc, c == 0);
        k_gemm_nt_bias<<<ggrid, 256, 0, stream>>>(
            h1c, (long)Tc * H_, Wih1, bih1, gi1,
            G3_, H_, tcShift);
        k_gru_scan_resident<<<B_, 512, 0, stream>>>(
            gi1, wl1, bhh1, hst1, nullptr, Tc, c == 0);
    }

    k_fc<<<10, 256, 0, stream>>>(hst1, Wfc, bfc, out);
}

// Round 6
// 9384.385 us; speedup vs baseline: 13.6159x; 4.5048x over previous
//
#include <hip/hip_runtime.h>
#include <cstddef>
#include <cstdint>

#define B_  256
#define T_  512
#define D_  128
#define H_  256
#define G3_ 768
#define C_  10

__device__ __forceinline__ float sigmoid_f(float x) {
    return 1.0f / (1.0f + __expf(-x));
}
__device__ __forceinline__ float tanh_f(float x) {
    return 1.0f - 2.0f / (__expf(2.0f * x) + 1.0f);
}

__device__ __forceinline__ unsigned int bf16_rne(float f) {
    unsigned int u = __float_as_uint(f);
    return (u + 0x7fffu + ((u >> 16) & 1u)) >> 16;   // round-to-nearest-even
}
__device__ __forceinline__ unsigned int pack2(float even, float odd) {
    return bf16_rne(even) | (bf16_rne(odd) << 16);
}
#define UNPK_EVEN(x) __uint_as_float((x) << 16)
#define UNPK_ODD(x)  __uint_as_float((x) & 0xffff0000u)

// ---------------------------------------------------------------------------
// Pack Whh[3H][H] fp32 -> bf16 stream layout for the 1024-thread scan.
// Scan lane t: w=t>>6, l=t&63, j=w*16+(l&15), k-quarter q=(t>>4)&3.
// Wl[(g*8+i)*1024 + t] = uint4 of 4 bf16 pairs: k = q*64 + 8i + 0..7, gate g.
// grid: 24 blocks (g*8+i) x 1024 threads. Total 393,216 B per layer.
// ---------------------------------------------------------------------------
__global__ void k_pack_whh(const float* __restrict__ Whh, uint4* __restrict__ Wl) {
    const int g = blockIdx.x >> 3;
    const int i = blockIdx.x & 7;
    const int t = threadIdx.x;
    const int j = ((t >> 6) << 4) + (t & 15);
    const int q = (t >> 4) & 3;
    const int kb = q * 64 + 8 * i;
    const float* row = Whh + (size_t)(g * H_ + j) * H_;
    uint4 u;
    u.x = pack2(row[kb + 0], row[kb + 1]);
    u.y = pack2(row[kb + 2], row[kb + 3]);
    u.z = pack2(row[kb + 4], row[kb + 5]);
    u.w = pack2(row[kb + 6], row[kb + 7]);
    Wl[(size_t)blockIdx.x * 1024 + t] = u;
}

// ---------------------------------------------------------------------------
// C[M,N] = A[M,K] @ W[N,K]^T + bias[N]  (fp32 NT, chunk-major A rows).
// ---------------------------------------------------------------------------
__global__ __launch_bounds__(256, 2) void k_gemm_nt_bias(
    const float* __restrict__ A, long Abstride,
    const float* __restrict__ W,
    const float* __restrict__ bias, float* __restrict__ C,
    int N, int K, int tcShift)
{
    __shared__ float As[16][128];
    __shared__ float Ws[16][64];
    const int tid = threadIdx.x;
    const int tx = tid & 15;
    const int ty = tid >> 4;
    const int m0 = blockIdx.y * 128;
    const int n0 = blockIdx.x * 64;
    const int arow = tid >> 1;
    const int ak   = (tid & 1) * 8;
    const int wrow = tid >> 2;
    const int wk   = (tid & 3) * 4;

    const int mask = (1 << tcShift) - 1;
    const int mg = m0 + arow;
    const float* Arow = A + (size_t)(mg >> tcShift) * Abstride + (size_t)(mg & mask) * K;
    const float* Wrow = W + (size_t)(n0 + wrow) * K;

    float acc[8][4] = {};

    for (int k0 = 0; k0 < K; k0 += 16) {
        float4 a0 = *(const float4*)&Arow[k0 + ak];
        float4 a1 = *(const float4*)&Arow[k0 + ak + 4];
        float4 wv = *(const float4*)&Wrow[k0 + wk];
        __syncthreads();
        As[ak + 0][arow] = a0.x; As[ak + 1][arow] = a0.y;
        As[ak + 2][arow] = a0.z; As[ak + 3][arow] = a0.w;
        As[ak + 4][arow] = a1.x; As[ak + 5][arow] = a1.y;
        As[ak + 6][arow] = a1.z; As[ak + 7][arow] = a1.w;
        Ws[wk + 0][wrow] = wv.x; Ws[wk + 1][wrow] = wv.y;
        Ws[wk + 2][wrow] = wv.z; Ws[wk + 3][wrow] = wv.w;
        __syncthreads();
#pragma unroll
        for (int kk = 0; kk < 16; kk++) {
            float a8[8], b4[4];
            *(float4*)&a8[0] = *(const float4*)&As[kk][ty * 8];
            *(float4*)&a8[4] = *(const float4*)&As[kk][ty * 8 + 4];
            *(float4*)&b4[0] = *(const float4*)&Ws[kk][tx * 4];
#pragma unroll
            for (int ii = 0; ii < 8; ii++)
#pragma unroll
                for (int jj = 0; jj < 4; jj++)
                    acc[ii][jj] = fmaf(a8[ii], b4[jj], acc[ii][jj]);
        }
    }

    float b4[4];
#pragma unroll
    for (int jj = 0; jj < 4; jj++) b4[jj] = bias[n0 + tx * 4 + jj];
#pragma unroll
    for (int ii = 0; ii < 8; ii++) {
        float4 v;
        v.x = acc[ii][0] + b4[0];
        v.y = acc[ii][1] + b4[1];
        v.z = acc[ii][2] + b4[2];
        v.w = acc[ii][3] + b4[3];
        *(float4*)&C[(size_t)(m0 + ty * 8 + ii) * N + n0 + tx * 4] = v;
    }
}

// ---------------------------------------------------------------------------
// Scan core: one block = 4 batch rows, 1024 thr (16 waves). Lane owns hidden
// unit j and k-quarter q; streams its 24 uint4 bf16 weights from L2 each step
// (393 KB/CU/step). h fp32, double-buffered in LDS; 2x shfl_xor combines the
// 4 k-quarters; q==0 lanes apply gates and publish. All register arrays are
// indexed by compile-time constants only (R4/R5 lesson: spills are fatal).
// ---------------------------------------------------------------------------
__device__ __forceinline__ void dot8s(float& acc, uint4 u, float4 hA, float4 hB) {
    acc = fmaf(UNPK_EVEN(u.x), hA.x, acc);
    acc = fmaf(UNPK_ODD(u.x),  hA.y, acc);
    acc = fmaf(UNPK_EVEN(u.y), hA.z, acc);
    acc = fmaf(UNPK_ODD(u.y),  hA.w, acc);
    acc = fmaf(UNPK_EVEN(u.z), hB.x, acc);
    acc = fmaf(UNPK_ODD(u.z),  hB.y, acc);
    acc = fmaf(UNPK_EVEN(u.w), hB.z, acc);
    acc = fmaf(UNPK_ODD(u.w),  hB.w, acc);
}

__device__ __forceinline__ void gru_scan_core(
    const float* __restrict__ gi,      // + b0*Tc*G3   [4 rows][Tc][3H]
    const uint4* __restrict__ Wl,      // [24][1024]
    const float* __restrict__ bhh,
    float* __restrict__ h_state,       // + b0*H
    float* __restrict__ out_seq,       // + b0*Tc*H or nullptr
    int Tc, int initZero,
    float (&hbuf)[2][4][H_])
{
    const int t = threadIdx.x;
    const int j = ((t >> 6) << 4) + (t & 15);
    const int q = (t >> 4) & 3;
    const int kb = q * 64;

    const float br = bhh[j];
    const float bz = bhh[H_ + j];
    const float bn = bhh[2 * H_ + j];

    if (q == 0) {
#pragma unroll
        for (int r = 0; r < 4; r++)
            hbuf[0][r][j] = initZero ? 0.0f : h_state[(size_t)r * H_ + j];
    }
    __syncthreads();

    const uint4* wlt = Wl + t;

    float gc[4][3];
    if (q == 0) {
#pragma unroll
        for (int r = 0; r < 4; r++) {
            const float* gp = gi + (size_t)r * Tc * G3_;
            gc[r][0] = gp[j];
            gc[r][1] = gp[H_ + j];
            gc[r][2] = gp[2 * H_ + j];
        }
    }

    int cur = 0;
    for (int tt = 0; tt < Tc; ++tt) {
        // issue next step's gi loads early (complete under the k-loop)
        float gnx[4][3];
        if (q == 0 && tt + 1 < Tc) {
#pragma unroll
            for (int r = 0; r < 4; r++) {
                const float* gp = gi + ((size_t)r * Tc + tt + 1) * G3_;
                gnx[r][0] = gp[j];
                gnx[r][1] = gp[H_ + j];
                gnx[r][2] = gp[2 * H_ + j];
            }
        }

        float hp[4];
        if (q == 0) {
#pragma unroll
            for (int r = 0; r < 4; r++) hp[r] = hbuf[cur][r][j];
        }

        float ar[4] = {}, az[4] = {}, an[4] = {};
#pragma unroll
        for (int i = 0; i < 8; i++) {
            uint4 wr = wlt[(size_t)(0 * 8 + i) * 1024];
            uint4 wz = wlt[(size_t)(1 * 8 + i) * 1024];
            uint4 wn = wlt[(size_t)(2 * 8 + i) * 1024];
            float4 hA[4], hB[4];
#pragma unroll
            for (int r = 0; r < 4; r++) {
                hA[r] = *(const float4*)&hbuf[cur][r][kb + 8 * i];
                hB[r] = *(const float4*)&hbuf[cur][r][kb + 8 * i + 4];
            }
#pragma unroll
            for (int r = 0; r < 4; r++) {
                dot8s(ar[r], wr, hA[r], hB[r]);
                dot8s(az[r], wz, hA[r], hB[r]);
                dot8s(an[r], wn, hA[r], hB[r]);
            }
        }

#pragma unroll
        for (int r = 0; r < 4; r++) {
            ar[r] += __shfl_xor(ar[r], 16, 64);
            ar[r] += __shfl_xor(ar[r], 32, 64);
            az[r] += __shfl_xor(az[r], 16, 64);
            az[r] += __shfl_xor(az[r], 32, 64);
            an[r] += __shfl_xor(an[r], 16, 64);
            an[r] += __shfl_xor(an[r], 32, 64);
        }

        if (q == 0) {
#pragma unroll
            for (int r = 0; r < 4; r++) {
                float rr = sigmoid_f(gc[r][0] + ar[r] + br);
                float zz = sigmoid_f(gc[r][1] + az[r] + bz);
                float nn = tanh_f(gc[r][2] + rr * (an[r] + bn)); // bhh_n in r-gate
                float hn = (1.0f - zz) * nn + zz * hp[r];
                hbuf[cur ^ 1][r][j] = hn;
                if (out_seq)
                    out_seq[((size_t)r * Tc + tt) * H_ + j] = hn;
                if (tt == Tc - 1)
                    h_state[(size_t)r * H_ + j] = hn;
            }
        }

#pragma unroll
        for (int r = 0; r < 4; r++) {
            gc[r][0] = gnx[r][0];
            gc[r][1] = gnx[r][1];
            gc[r][2] = gnx[r][2];
        }
        __syncthreads();
        cur ^= 1;
    }
}

// Fused layer-pipelined scan: blocks 0..63 run layer0 chunk c; blocks 64..127
// run layer1 chunk c-1 (independent given the stream ordering). 1024 threads
// (16 waves, >=65 VGPR) guarantees 1 block/CU -> 128 CUs, no co-residency.
__global__ __launch_bounds__(1024, 1) void k_gru_scan_fused(
    const float* __restrict__ gi0, const uint4* __restrict__ wl0,
    const float* __restrict__ bhh0, float* __restrict__ hst0,
    float* __restrict__ h1c,
    const float* __restrict__ gi1, const uint4* __restrict__ wl1,
    const float* __restrict__ bhh1, float* __restrict__ hst1,
    int Tc, int do0, int do1, int init0, int init1)
{
    __shared__ __align__(16) float hbuf[2][4][H_];
    const int blk = blockIdx.x;
    if (blk < 64) {
        if (!do0) return;
        const int b0 = blk * 4;
        gru_scan_core(gi0 + (size_t)b0 * Tc * G3_, wl0, bhh0,
                      hst0 + (size_t)b0 * H_, h1c + (size_t)b0 * Tc * H_,
                      Tc, init0, hbuf);
    } else {
        if (!do1) return;
        const int b0 = (blk - 64) * 4;
        gru_scan_core(gi1 + (size_t)b0 * Tc * G3_, wl1, bhh1,
                      hst1 + (size_t)b0 * H_, nullptr,
                      Tc, init1, hbuf);
    }
}

// ---------------------------------------------------------------------------
__global__ void k_fc(const float* __restrict__ h, const float* __restrict__ Wfc,
                     const float* __restrict__ bfc, float* __restrict__ out)
{
    int idx = blockIdx.x * blockDim.x + threadIdx.x;
    if (idx >= B_ * C_) return;
    int b = idx / C_, c = idx % C_;
    const float* hp = h + (size_t)b * H_;
    const float* wp = Wfc + (size_t)c * H_;
    float s = bfc[c];
#pragma unroll 4
    for (int k = 0; k < H_; k++) s = fmaf(hp[k], wp[k], s);
    out[idx] = s;
}

// ---------------------------------------------------------------------------
extern "C" void kernel_launch(void* const* d_in, const int* in_sizes, int n_in,
                              void* d_out, int out_size, void* d_ws, size_t ws_size,
                              hipStream_t stream)
{
    const float* x    = (const float*)d_in[0];
    const float* Wih0 = (const float*)d_in[1];
    const float* Whh0 = (const float*)d_in[2];
    const float* bih0 = (const float*)d_in[3];
    const float* bhh0 = (const float*)d_in[4];
    const float* Wih1 = (const float*)d_in[5];
    const float* Whh1 = (const float*)d_in[6];
    const float* bih1 = (const float*)d_in[7];
    const float* bhh1 = (const float*)d_in[8];
    const float* Wfc  = (const float*)d_in[9];
    const float* bfc  = (const float*)d_in[10];
    float* out = (float*)d_out;

    const size_t wlBytes = (size_t)24 * 1024 * sizeof(uint4);   // 393,216 B

    // ---- largest power-of-two T-chunk that fits ws_size -------------------
    const size_t fixedB = 2 * wlBytes + 2 * (size_t)B_ * H_ * 4 + 8192;
    int Tc = 128, tcShift = 7;
    while (Tc > 1) {
        size_t need = fixedB
                    + 2 * (size_t)B_ * Tc * G3_ * 4    // gi0, gi1 chunks
                    + (size_t)B_ * Tc * H_ * 4;        // h1 chunk
        if (need <= ws_size) break;
        Tc >>= 1; tcShift--;
    }
    const int nChunks = T_ / Tc;

    char* ws = (char*)d_ws;
    size_t off = 0;
    auto alloc = [&](size_t bytes) { char* p = ws + off; off += (bytes + 255) & ~(size_t)255; return p; };
    float* gi0  = (float*)alloc((size_t)B_ * Tc * G3_ * 4);
    float* gi1  = (float*)alloc((size_t)B_ * Tc * G3_ * 4);
    float* h1c  = (float*)alloc((size_t)B_ * Tc * H_ * 4);
    uint4* wl0  = (uint4*)alloc(wlBytes);
    uint4* wl1  = (uint4*)alloc(wlBytes);
    float* hst0 = (float*)alloc((size_t)B_ * H_ * 4);
    float* hst1 = (float*)alloc((size_t)B_ * H_ * 4);

    k_pack_whh<<<24, 1024, 0, stream>>>(Whh0, wl0);
    k_pack_whh<<<24, 1024, 0, stream>>>(Whh1, wl1);

    const dim3 ggrid(G3_ / 64, (B_ * Tc) / 128);

    // software pipeline: fused launch c runs scan0(c) and scan1(c-1)
    k_gemm_nt_bias<<<ggrid, 256, 0, stream>>>(
        x, (long)T_ * D_, Wih0, bih0, gi0, G3_, D_, tcShift);
    k_gru_scan_fused<<<128, 1024, 0, stream>>>(
        gi0, wl0, bhh0, hst0, h1c, gi1, wl1, bhh1, hst1,
        Tc, 1, 0, 1, 0);

    for (int c = 1; c < nChunks; ++c) {
        k_gemm_nt_bias<<<ggrid, 256, 0, stream>>>(
            h1c, (long)Tc * H_, Wih1, bih1, gi1, G3_, H_, tcShift);  // chunk c-1
        k_gemm_nt_bias<<<ggrid, 256, 0, stream>>>(
            x + (size_t)c * Tc * D_, (long)T_ * D_, Wih0, bih0, gi0,
            G3_, D_, tcShift);                                        // chunk c
        k_gru_scan_fused<<<128, 1024, 0, stream>>>(
            gi0, wl0, bhh0, hst0, h1c, gi1, wl1, bhh1, hst1,
            Tc, 1, 1, 0, c == 1);
    }

    k_gemm_nt_bias<<<ggrid, 256, 0, stream>>>(
        h1c, (long)Tc * H_, Wih1, bih1, gi1, G3_, H_, tcShift);      // last chunk
    k_gru_scan_fused<<<128, 1024, 0, stream>>>(
        gi0, wl0, bhh0, hst0, h1c, gi1, wl1, bhh1, hst1,
        Tc, 0, 1, 0, nChunks == 1);

    k_fc<<<10, 256, 0, stream>>>(hst1, Wfc, bfc, out);
}

// Round 7
// 8479.103 us; speedup vs baseline: 15.0696x; 1.1068x over previous
//
#include <hip/hip_runtime.h>
#include <hip/hip_fp16.h>
#include <cstddef>
#include <cstdint>

#define B_  256
#define T_  512
#define D_  128
#define H_  256
#define G3_ 768
#define C_  10

__device__ __forceinline__ float sigmoid_f(float x) {
    return 1.0f / (1.0f + __expf(-x));
}
__device__ __forceinline__ float tanh_f(float x) {
    return 1.0f - 2.0f / (__expf(2.0f * x) + 1.0f);
}

__device__ __forceinline__ unsigned int packh2(float a, float b) {
    unsigned short lo = __half_as_ushort(__float2half(a));   // k even -> lo16
    unsigned short hi = __half_as_ushort(__float2half(b));   // k odd  -> hi16
    return (unsigned int)lo | ((unsigned int)hi << 16);
}

// ---------------------------------------------------------------------------
// Pack Whh[3H][H] fp32 -> f16 resident layout for the 512-thread scan.
// Scan lane t: wave w=t>>6, lane l=t&63, j=w*32+(l&31), k-half q=(l>>5)&1.
// Wl[(g*16+i)*512 + t] = uint4 of 8 f16 weights: gate g, k = q*128+8i+0..7.
// grid: 48 blocks x 512 threads. 393,216 B per layer.
// ---------------------------------------------------------------------------
__global__ void k_pack_whh(const float* __restrict__ Whh, uint4* __restrict__ Wl) {
    const int g = blockIdx.x >> 4;
    const int i = blockIdx.x & 15;
    const int t = threadIdx.x;
    const int j = ((t >> 6) << 5) + (t & 31);
    const int q = (t >> 5) & 1;
    const int kb = q * 128 + 8 * i;
    const float* row = Whh + (size_t)(g * H_ + j) * H_;
    uint4 u;
    u.x = packh2(row[kb + 0], row[kb + 1]);
    u.y = packh2(row[kb + 2], row[kb + 3]);
    u.z = packh2(row[kb + 4], row[kb + 5]);
    u.w = packh2(row[kb + 6], row[kb + 7]);
    Wl[(size_t)blockIdx.x * 512 + t] = u;
}

// ---------------------------------------------------------------------------
// C[M,N] = A[M,K] @ W[N,K]^T + bias[N]  (fp32 NT, chunk-major A rows).
// ---------------------------------------------------------------------------
__global__ __launch_bounds__(256, 2) void k_gemm_nt_bias(
    const float* __restrict__ A, long Abstride,
    const float* __restrict__ W,
    const float* __restrict__ bias, float* __restrict__ C,
    int N, int K, int tcShift)
{
    __shared__ float As[16][128];
    __shared__ float Ws[16][64];
    const int tid = threadIdx.x;
    const int tx = tid & 15;
    const int ty = tid >> 4;
    const int m0 = blockIdx.y * 128;
    const int n0 = blockIdx.x * 64;
    const int arow = tid >> 1;
    const int ak   = (tid & 1) * 8;
    const int wrow = tid >> 2;
    const int wk   = (tid & 3) * 4;

    const int mask = (1 << tcShift) - 1;
    const int mg = m0 + arow;
    const float* Arow = A + (size_t)(mg >> tcShift) * Abstride + (size_t)(mg & mask) * K;
    const float* Wrow = W + (size_t)(n0 + wrow) * K;

    float acc[8][4] = {};

    for (int k0 = 0; k0 < K; k0 += 16) {
        float4 a0 = *(const float4*)&Arow[k0 + ak];
        float4 a1 = *(const float4*)&Arow[k0 + ak + 4];
        float4 wv = *(const float4*)&Wrow[k0 + wk];
        __syncthreads();
        As[ak + 0][arow] = a0.x; As[ak + 1][arow] = a0.y;
        As[ak + 2][arow] = a0.z; As[ak + 3][arow] = a0.w;
        As[ak + 4][arow] = a1.x; As[ak + 5][arow] = a1.y;
        As[ak + 6][arow] = a1.z; As[ak + 7][arow] = a1.w;
        Ws[wk + 0][wrow] = wv.x; Ws[wk + 1][wrow] = wv.y;
        Ws[wk + 2][wrow] = wv.z; Ws[wk + 3][wrow] = wv.w;
        __syncthreads();
#pragma unroll
        for (int kk = 0; kk < 16; kk++) {
            float a8[8], b4[4];
            *(float4*)&a8[0] = *(const float4*)&As[kk][ty * 8];
            *(float4*)&a8[4] = *(const float4*)&As[kk][ty * 8 + 4];
            *(float4*)&b4[0] = *(const float4*)&Ws[kk][tx * 4];
#pragma unroll
            for (int ii = 0; ii < 8; ii++)
#pragma unroll
                for (int jj = 0; jj < 4; jj++)
                    acc[ii][jj] = fmaf(a8[ii], b4[jj], acc[ii][jj]);
        }
    }

    float b4[4];
#pragma unroll
    for (int jj = 0; jj < 4; jj++) b4[jj] = bias[n0 + tx * 4 + jj];
#pragma unroll
    for (int ii = 0; ii < 8; ii++) {
        float4 v;
        v.x = acc[ii][0] + b4[0];
        v.y = acc[ii][1] + b4[1];
        v.z = acc[ii][2] + b4[2];
        v.w = acc[ii][3] + b4[3];
        *(float4*)&C[(size_t)(m0 + ty * 8 + ii) * N + n0 + tx * 4] = v;
    }
}

// ---------------------------------------------------------------------------
// VGPR-resident scan core. Block = 2 batch rows, 512 thr (8 waves, 2/SIMD,
// 256-VGPR budget per __launch_bounds__(512,1) -- R5's failure was (512,2)
// which caps at 128 and spills). Lane owns hidden unit j and k-half q; its
// 384 f16 weights live in 48 uint4 REGISTERS all dispatch (zero per-step
// weight traffic; R6's 4.8 GB/dispatch L2-miss stream eliminated).
// fmaf(__low2float(h2),...) folds to v_fma_mix_f32 (no unpack ops).
// h fp32 double-buffered in LDS: 2 distinct wave addresses -> conflict-free.
// ---------------------------------------------------------------------------
__device__ __forceinline__ void dot8h(float& acc, const uint4& u,
                                      const float4& hA, const float4& hB) {
    const __half2 p0 = *reinterpret_cast<const __half2*>(&u.x);
    const __half2 p1 = *reinterpret_cast<const __half2*>(&u.y);
    const __half2 p2 = *reinterpret_cast<const __half2*>(&u.z);
    const __half2 p3 = *reinterpret_cast<const __half2*>(&u.w);
    acc = fmaf(__low2float(p0),  hA.x, acc);
    acc = fmaf(__high2float(p0), hA.y, acc);
    acc = fmaf(__low2float(p1),  hA.z, acc);
    acc = fmaf(__high2float(p1), hA.w, acc);
    acc = fmaf(__low2float(p2),  hB.x, acc);
    acc = fmaf(__high2float(p2), hB.y, acc);
    acc = fmaf(__low2float(p3),  hB.z, acc);
    acc = fmaf(__high2float(p3), hB.w, acc);
}

__device__ __forceinline__ void gru_scan_core(
    const float* __restrict__ gi,      // + b0*Tc*G3   [2 rows][Tc][3H]
    const uint4* __restrict__ Wl,      // [48][512]
    const float* __restrict__ bhh,
    float* __restrict__ h_state,       // + b0*H
    float* __restrict__ out_seq,       // + b0*Tc*H or nullptr
    int Tc, int initZero,
    float (&hbuf)[2][2][H_])
{
    const int t = threadIdx.x;
    const int j = ((t >> 6) << 5) + (t & 31);
    const int q = (t >> 5) & 1;
    const int kb = q * 128;
    const bool lead = (q == 0);

    // ---- resident weights: 48 uint4 = 192 VGPRs, compile-time indices ----
    uint4 wq[48];
    {
        const uint4* wlt = Wl + t;
#pragma unroll
        for (int idx = 0; idx < 48; idx++) wq[idx] = wlt[(size_t)idx * 512];
    }

    const float br = bhh[j];
    const float bz = bhh[H_ + j];
    const float bn = bhh[2 * H_ + j];

    if (lead) {
#pragma unroll
        for (int r = 0; r < 2; r++)
            hbuf[0][r][j] = initZero ? 0.0f : h_state[(size_t)r * H_ + j];
    }
    __syncthreads();

    float gc[2][3] = {};
    if (lead) {
#pragma unroll
        for (int r = 0; r < 2; r++) {
            const float* gp = gi + (size_t)r * Tc * G3_;
            gc[r][0] = gp[j];
            gc[r][1] = gp[H_ + j];
            gc[r][2] = gp[2 * H_ + j];
        }
    }

    int cur = 0;
    for (int tt = 0; tt < Tc; ++tt) {
        float gnx[2][3] = {};
        if (lead && tt + 1 < Tc) {
#pragma unroll
            for (int r = 0; r < 2; r++) {
                const float* gp = gi + ((size_t)r * Tc + tt + 1) * G3_;
                gnx[r][0] = gp[j];
                gnx[r][1] = gp[H_ + j];
                gnx[r][2] = gp[2 * H_ + j];
            }
        }

        float hp[2];
        if (lead) {
            hp[0] = hbuf[cur][0][j];
            hp[1] = hbuf[cur][1][j];
        }

        float ar0 = 0.f, az0 = 0.f, an0 = 0.f;
        float ar1 = 0.f, az1 = 0.f, an1 = 0.f;
#pragma unroll
        for (int i = 0; i < 16; i++) {
            float4 hA0 = *(const float4*)&hbuf[cur][0][kb + 8 * i];
            float4 hB0 = *(const float4*)&hbuf[cur][0][kb + 8 * i + 4];
            float4 hA1 = *(const float4*)&hbuf[cur][1][kb + 8 * i];
            float4 hB1 = *(const float4*)&hbuf[cur][1][kb + 8 * i + 4];
            dot8h(ar0, wq[0 * 16 + i], hA0, hB0);
            dot8h(ar1, wq[0 * 16 + i], hA1, hB1);
            dot8h(az0, wq[1 * 16 + i], hA0, hB0);
            dot8h(az1, wq[1 * 16 + i], hA1, hB1);
            dot8h(an0, wq[2 * 16 + i], hA0, hB0);
            dot8h(an1, wq[2 * 16 + i], hA1, hB1);
        }

        ar0 += __shfl_xor(ar0, 32, 64);
        az0 += __shfl_xor(az0, 32, 64);
        an0 += __shfl_xor(an0, 32, 64);
        ar1 += __shfl_xor(ar1, 32, 64);
        az1 += __shfl_xor(az1, 32, 64);
        an1 += __shfl_xor(an1, 32, 64);

        if (lead) {
            float rr0 = sigmoid_f(gc[0][0] + ar0 + br);
            float zz0 = sigmoid_f(gc[0][1] + az0 + bz);
            float nn0 = tanh_f(gc[0][2] + rr0 * (an0 + bn));  // bhh_n in r-gate
            float hn0 = (1.0f - zz0) * nn0 + zz0 * hp[0];
            float rr1 = sigmoid_f(gc[1][0] + ar1 + br);
            float zz1 = sigmoid_f(gc[1][1] + az1 + bz);
            float nn1 = tanh_f(gc[1][2] + rr1 * (an1 + bn));
            float hn1 = (1.0f - zz1) * nn1 + zz1 * hp[1];
            hbuf[cur ^ 1][0][j] = hn0;
            hbuf[cur ^ 1][1][j] = hn1;
            if (out_seq) {
                out_seq[((size_t)0 * Tc + tt) * H_ + j] = hn0;
                out_seq[((size_t)1 * Tc + tt) * H_ + j] = hn1;
            }
            if (tt == Tc - 1) {
                h_state[0 * H_ + j] = hn0;
                h_state[1 * H_ + j] = hn1;
            }
#pragma unroll
            for (int r = 0; r < 2; r++) {
                gc[r][0] = gnx[r][0];
                gc[r][1] = gnx[r][1];
                gc[r][2] = gnx[r][2];
            }
        }
        __syncthreads();
        cur ^= 1;
    }
}

// Fused layer-pipelined scan: blocks 0..127 -> layer0 chunk c (2 rows each),
// blocks 128..255 -> layer1 chunk c-1. 256 blocks x 512 thr = 1 block/CU on
// all 256 CUs at 2 waves/SIMD (256-VGPR budget).
__global__ __launch_bounds__(512, 1) void k_gru_scan_fused(
    const float* __restrict__ gi0, const uint4* __restrict__ wl0,
    const float* __restrict__ bhh0, float* __restrict__ hst0,
    float* __restrict__ h1c,
    const float* __restrict__ gi1, const uint4* __restrict__ wl1,
    const float* __restrict__ bhh1, float* __restrict__ hst1,
    int Tc, int do0, int do1, int init0, int init1)
{
    __shared__ __align__(16) float hbuf[2][2][H_];
    const int blk = blockIdx.x;
    if (blk < 128) {
        if (!do0) return;
        const int b0 = blk * 2;
        gru_scan_core(gi0 + (size_t)b0 * Tc * G3_, wl0, bhh0,
                      hst0 + (size_t)b0 * H_, h1c + (size_t)b0 * Tc * H_,
                      Tc, init0, hbuf);
    } else {
        if (!do1) return;
        const int b0 = (blk - 128) * 2;
        gru_scan_core(gi1 + (size_t)b0 * Tc * G3_, wl1, bhh1,
                      hst1 + (size_t)b0 * H_, nullptr,
                      Tc, init1, hbuf);
    }
}

// ---------------------------------------------------------------------------
__global__ void k_fc(const float* __restrict__ h, const float* __restrict__ Wfc,
                     const float* __restrict__ bfc, float* __restrict__ out)
{
    int idx = blockIdx.x * blockDim.x + threadIdx.x;
    if (idx >= B_ * C_) return;
    int b = idx / C_, c = idx % C_;
    const float* hp = h + (size_t)b * H_;
    const float* wp = Wfc + (size_t)c * H_;
    float s = bfc[c];
#pragma unroll 4
    for (int k = 0; k < H_; k++) s = fmaf(hp[k], wp[k], s);
    out[idx] = s;
}

// ---------------------------------------------------------------------------
extern "C" void kernel_launch(void* const* d_in, const int* in_sizes, int n_in,
                              void* d_out, int out_size, void* d_ws, size_t ws_size,
                              hipStream_t stream)
{
    const float* x    = (const float*)d_in[0];
    const float* Wih0 = (const float*)d_in[1];
    const float* Whh0 = (const float*)d_in[2];
    const float* bih0 = (const float*)d_in[3];
    const float* bhh0 = (const float*)d_in[4];
    const float* Wih1 = (const float*)d_in[5];
    const float* Whh1 = (const float*)d_in[6];
    const float* bih1 = (const float*)d_in[7];
    const float* bhh1 = (const float*)d_in[8];
    const float* Wfc  = (const float*)d_in[9];
    const float* bfc  = (const float*)d_in[10];
    float* out = (float*)d_out;

    const size_t wlBytes = (size_t)48 * 512 * sizeof(uint4);   // 393,216 B

    // ---- largest power-of-two T-chunk that fits ws_size -------------------
    const size_t fixedB = 2 * wlBytes + 2 * (size_t)B_ * H_ * 4 + 8192;
    int Tc = 128, tcShift = 7;
    while (Tc > 1) {
        size_t need = fixedB
                    + 2 * (size_t)B_ * Tc * G3_ * 4    // gi0, gi1 chunks
                    + (size_t)B_ * Tc * H_ * 4;        // h1 chunk
        if (need <= ws_size) break;
        Tc >>= 1; tcShift--;
    }
    const int nChunks = T_ / Tc;

    char* ws = (char*)d_ws;
    size_t off = 0;
    auto alloc = [&](size_t bytes) { char* p = ws + off; off += (bytes + 255) & ~(size_t)255; return p; };
    float* gi0  = (float*)alloc((size_t)B_ * Tc * G3_ * 4);
    float* gi1  = (float*)alloc((size_t)B_ * Tc * G3_ * 4);
    float* h1c  = (float*)alloc((size_t)B_ * Tc * H_ * 4);
    uint4* wl0  = (uint4*)alloc(wlBytes);
    uint4* wl1  = (uint4*)alloc(wlBytes);
    float* hst0 = (float*)alloc((size_t)B_ * H_ * 4);
    float* hst1 = (float*)alloc((size_t)B_ * H_ * 4);

    k_pack_whh<<<48, 512, 0, stream>>>(Whh0, wl0);
    k_pack_whh<<<48, 512, 0, stream>>>(Whh1, wl1);

    const dim3 ggrid(G3_ / 64, (B_ * Tc) / 128);

    // software pipeline: fused launch c runs scan0(c) and scan1(c-1)
    k_gemm_nt_bias<<<ggrid, 256, 0, stream>>>(
        x, (long)T_ * D_, Wih0, bih0, gi0, G3_, D_, tcShift);
    k_gru_scan_fused<<<256, 512, 0, stream>>>(
        gi0, wl0, bhh0, hst0, h1c, gi1, wl1, bhh1, hst1,
        Tc, 1, 0, 1, 0);

    for (int c = 1; c < nChunks; ++c) {
        k_gemm_nt_bias<<<ggrid, 256, 0, stream>>>(
            h1c, (long)Tc * H_, Wih1, bih1, gi1, G3_, H_, tcShift);  // chunk c-1
        k_gemm_nt_bias<<<ggrid, 256, 0, stream>>>(
            x + (size_t)c * Tc * D_, (long)T_ * D_, Wih0, bih0, gi0,
            G3_, D_, tcShift);                                        // chunk c
        k_gru_scan_fused<<<256, 512, 0, stream>>>(
            gi0, wl0, bhh0, hst0, h1c, gi1, wl1, bhh1, hst1,
            Tc, 1, 1, 0, c == 1);
    }

    k_gemm_nt_bias<<<ggrid, 256, 0, stream>>>(
        h1c, (long)Tc * H_, Wih1, bih1, gi1, G3_, H_, tcShift);      // last chunk
    k_gru_scan_fused<<<256, 512, 0, stream>>>(
        gi0, wl0, bhh0, hst0, h1c, gi1, wl1, bhh1, hst1,
        Tc, 0, 1, 0, nChunks == 1);

    k_fc<<<10, 256, 0, stream>>>(hst1, Wfc, bfc, out);
}

// Round 8
// 8470.013 us; speedup vs baseline: 15.0858x; 1.0011x over previous
//
#include <hip/hip_runtime.h>
#include <hip/hip_fp16.h>
#include <cstddef>
#include <cstdint>

#define B_  256
#define T_  512
#define D_  128
#define H_  256
#define G3_ 768
#define C_  10

__device__ __forceinline__ float sigmoid_f(float x) {
    return 1.0f / (1.0f + __expf(-x));
}
__device__ __forceinline__ float tanh_f(float x) {
    return 1.0f - 2.0f / (__expf(2.0f * x) + 1.0f);
}

__device__ __forceinline__ unsigned int packh2(float a, float b) {
    unsigned short lo = __half_as_ushort(__float2half(a));   // k even -> lo16
    unsigned short hi = __half_as_ushort(__float2half(b));   // k odd  -> hi16
    return (unsigned int)lo | ((unsigned int)hi << 16);
}

// ---------------------------------------------------------------------------
// Pack Whh[3H][H] fp32 -> f16 resident layout for the 512-thread scan.
// Scan lane t: wave w=t>>6, lane l=t&63, j=w*32+(l&31), k-half q=(l>>5)&1.
// Wl[(g*16+i)*512 + t] = uint4 of 8 f16 weights: gate g, k = q*128+8i+0..7.
// grid: 48 blocks x 512 threads. 393,216 B per layer.
// ---------------------------------------------------------------------------
__global__ void k_pack_whh(const float* __restrict__ Whh, uint4* __restrict__ Wl) {
    const int g = blockIdx.x >> 4;
    const int i = blockIdx.x & 15;
    const int t = threadIdx.x;
    const int j = ((t >> 6) << 5) + (t & 31);
    const int q = (t >> 5) & 1;
    const int kb = q * 128 + 8 * i;
    const float* row = Whh + (size_t)(g * H_ + j) * H_;
    uint4 u;
    u.x = packh2(row[kb + 0], row[kb + 1]);
    u.y = packh2(row[kb + 2], row[kb + 3]);
    u.z = packh2(row[kb + 4], row[kb + 5]);
    u.w = packh2(row[kb + 6], row[kb + 7]);
    Wl[(size_t)blockIdx.x * 512 + t] = u;
}

// ---------------------------------------------------------------------------
// C[M,N] = A[M,K] @ W[N,K]^T + bias[N]  (fp32 NT, chunk-major A rows).
// ---------------------------------------------------------------------------
__global__ __launch_bounds__(256, 2) void k_gemm_nt_bias(
    const float* __restrict__ A, long Abstride,
    const float* __restrict__ W,
    const float* __restrict__ bias, float* __restrict__ C,
    int N, int K, int tcShift)
{
    __shared__ float As[16][128];
    __shared__ float Ws[16][64];
    const int tid = threadIdx.x;
    const int tx = tid & 15;
    const int ty = tid >> 4;
    const int m0 = blockIdx.y * 128;
    const int n0 = blockIdx.x * 64;
    const int arow = tid >> 1;
    const int ak   = (tid & 1) * 8;
    const int wrow = tid >> 2;
    const int wk   = (tid & 3) * 4;

    const int mask = (1 << tcShift) - 1;
    const int mg = m0 + arow;
    const float* Arow = A + (size_t)(mg >> tcShift) * Abstride + (size_t)(mg & mask) * K;
    const float* Wrow = W + (size_t)(n0 + wrow) * K;

    float acc[8][4] = {};

    for (int k0 = 0; k0 < K; k0 += 16) {
        float4 a0 = *(const float4*)&Arow[k0 + ak];
        float4 a1 = *(const float4*)&Arow[k0 + ak + 4];
        float4 wv = *(const float4*)&Wrow[k0 + wk];
        __syncthreads();
        As[ak + 0][arow] = a0.x; As[ak + 1][arow] = a0.y;
        As[ak + 2][arow] = a0.z; As[ak + 3][arow] = a0.w;
        As[ak + 4][arow] = a1.x; As[ak + 5][arow] = a1.y;
        As[ak + 6][arow] = a1.z; As[ak + 7][arow] = a1.w;
        Ws[wk + 0][wrow] = wv.x; Ws[wk + 1][wrow] = wv.y;
        Ws[wk + 2][wrow] = wv.z; Ws[wk + 3][wrow] = wv.w;
        __syncthreads();
#pragma unroll
        for (int kk = 0; kk < 16; kk++) {
            float a8[8], b4[4];
            *(float4*)&a8[0] = *(const float4*)&As[kk][ty * 8];
            *(float4*)&a8[4] = *(const float4*)&As[kk][ty * 8 + 4];
            *(float4*)&b4[0] = *(const float4*)&Ws[kk][tx * 4];
#pragma unroll
            for (int ii = 0; ii < 8; ii++)
#pragma unroll
                for (int jj = 0; jj < 4; jj++)
                    acc[ii][jj] = fmaf(a8[ii], b4[jj], acc[ii][jj]);
        }
    }

    float b4[4];
#pragma unroll
    for (int jj = 0; jj < 4; jj++) b4[jj] = bias[n0 + tx * 4 + jj];
#pragma unroll
    for (int ii = 0; ii < 8; ii++) {
        float4 v;
        v.x = acc[ii][0] + b4[0];
        v.y = acc[ii][1] + b4[1];
        v.z = acc[ii][2] + b4[2];
        v.w = acc[ii][3] + b4[3];
        *(float4*)&C[(size_t)(m0 + ty * 8 + ii) * N + n0 + tx * 4] = v;
    }
}

// ---------------------------------------------------------------------------
// VGPR-resident scan core, occupancy-pinned. Empirical law (R4/R6/R7):
// without amdgpu_waves_per_eu the allocator caps VGPRs at 65536/blockDim
// (targets 2 blocks/CU) -> 512-thr blocks get 128 regs and the 192-reg
// weight array spills (R7: FETCH 6.2 GB/dispatch). waves_per_eu(1,2) at 512
// threads (8 waves = 2/SIMD) legalizes a 256-VGPR budget so the 48 uint4
// stay resident: zero per-step weight traffic.
// Lane owns (j, k-half q); h fp32 double-buffered in LDS (2 wave addresses
// -> 2-way aliasing = free); q-halves combined with one shfl_xor(32).
// ---------------------------------------------------------------------------
__device__ __forceinline__ void dot8h(float& acc, const uint4& u,
                                      const float4& hA, const float4& hB) {
    const __half2 p0 = *reinterpret_cast<const __half2*>(&u.x);
    const __half2 p1 = *reinterpret_cast<const __half2*>(&u.y);
    const __half2 p2 = *reinterpret_cast<const __half2*>(&u.z);
    const __half2 p3 = *reinterpret_cast<const __half2*>(&u.w);
    acc = fmaf(__low2float(p0),  hA.x, acc);
    acc = fmaf(__high2float(p0), hA.y, acc);
    acc = fmaf(__low2float(p1),  hA.z, acc);
    acc = fmaf(__high2float(p1), hA.w, acc);
    acc = fmaf(__low2float(p2),  hB.x, acc);
    acc = fmaf(__high2float(p2), hB.y, acc);
    acc = fmaf(__low2float(p3),  hB.z, acc);
    acc = fmaf(__high2float(p3), hB.w, acc);
}

__device__ __forceinline__ void gru_scan_core(
    const float* __restrict__ gi,      // + b0*Tc*G3   [2 rows][Tc][3H]
    const uint4* __restrict__ Wl,      // [48][512]
    const float* __restrict__ bhh,
    float* __restrict__ h_state,       // + b0*H
    float* __restrict__ out_seq,       // + b0*Tc*H or nullptr
    int Tc, int initZero,
    float (&hbuf)[2][2][H_])
{
    const int t = threadIdx.x;
    const int j = ((t >> 6) << 5) + (t & 31);
    const int q = (t >> 5) & 1;
    const int kb = q * 128;
    const bool lead = (q == 0);

    // ---- resident weights: 48 uint4 = 192 VGPRs, compile-time indices ----
    uint4 wq[48];
    {
        const uint4* wlt = Wl + t;
#pragma unroll
        for (int idx = 0; idx < 48; idx++) wq[idx] = wlt[(size_t)idx * 512];
    }

    const float br = bhh[j];
    const float bz = bhh[H_ + j];
    const float bn = bhh[2 * H_ + j];

    if (lead) {
#pragma unroll
        for (int r = 0; r < 2; r++)
            hbuf[0][r][j] = initZero ? 0.0f : h_state[(size_t)r * H_ + j];
    }
    __syncthreads();

    float gc[2][3] = {};
    if (lead) {
#pragma unroll
        for (int r = 0; r < 2; r++) {
            const float* gp = gi + (size_t)r * Tc * G3_;
            gc[r][0] = gp[j];
            gc[r][1] = gp[H_ + j];
            gc[r][2] = gp[2 * H_ + j];
        }
    }

    int cur = 0;
    for (int tt = 0; tt < Tc; ++tt) {
        float gnx[2][3] = {};
        if (lead && tt + 1 < Tc) {
#pragma unroll
            for (int r = 0; r < 2; r++) {
                const float* gp = gi + ((size_t)r * Tc + tt + 1) * G3_;
                gnx[r][0] = gp[j];
                gnx[r][1] = gp[H_ + j];
                gnx[r][2] = gp[2 * H_ + j];
            }
        }

        float hp[2];
        if (lead) {
            hp[0] = hbuf[cur][0][j];
            hp[1] = hbuf[cur][1][j];
        }

        float ar0 = 0.f, az0 = 0.f, an0 = 0.f;
        float ar1 = 0.f, az1 = 0.f, an1 = 0.f;
#pragma unroll
        for (int i = 0; i < 16; i++) {
            float4 hA0 = *(const float4*)&hbuf[cur][0][kb + 8 * i];
            float4 hB0 = *(const float4*)&hbuf[cur][0][kb + 8 * i + 4];
            float4 hA1 = *(const float4*)&hbuf[cur][1][kb + 8 * i];
            float4 hB1 = *(const float4*)&hbuf[cur][1][kb + 8 * i + 4];
            dot8h(ar0, wq[0 * 16 + i], hA0, hB0);
            dot8h(ar1, wq[0 * 16 + i], hA1, hB1);
            dot8h(az0, wq[1 * 16 + i], hA0, hB0);
            dot8h(az1, wq[1 * 16 + i], hA1, hB1);
            dot8h(an0, wq[2 * 16 + i], hA0, hB0);
            dot8h(an1, wq[2 * 16 + i], hA1, hB1);
        }

        ar0 += __shfl_xor(ar0, 32, 64);
        az0 += __shfl_xor(az0, 32, 64);
        an0 += __shfl_xor(an0, 32, 64);
        ar1 += __shfl_xor(ar1, 32, 64);
        az1 += __shfl_xor(az1, 32, 64);
        an1 += __shfl_xor(an1, 32, 64);

        if (lead) {
            float rr0 = sigmoid_f(gc[0][0] + ar0 + br);
            float zz0 = sigmoid_f(gc[0][1] + az0 + bz);
            float nn0 = tanh_f(gc[0][2] + rr0 * (an0 + bn));  // bhh_n in r-gate
            float hn0 = (1.0f - zz0) * nn0 + zz0 * hp[0];
            float rr1 = sigmoid_f(gc[1][0] + ar1 + br);
            float zz1 = sigmoid_f(gc[1][1] + az1 + bz);
            float nn1 = tanh_f(gc[1][2] + rr1 * (an1 + bn));
            float hn1 = (1.0f - zz1) * nn1 + zz1 * hp[1];
            hbuf[cur ^ 1][0][j] = hn0;
            hbuf[cur ^ 1][1][j] = hn1;
            if (out_seq) {
                out_seq[((size_t)0 * Tc + tt) * H_ + j] = hn0;
                out_seq[((size_t)1 * Tc + tt) * H_ + j] = hn1;
            }
            if (tt == Tc - 1) {
                h_state[0 * H_ + j] = hn0;
                h_state[1 * H_ + j] = hn1;
            }
#pragma unroll
            for (int r = 0; r < 2; r++) {
                gc[r][0] = gnx[r][0];
                gc[r][1] = gnx[r][1];
                gc[r][2] = gnx[r][2];
            }
        }
        __syncthreads();
        cur ^= 1;
    }
}

// Fused layer-pipelined scan: blocks 0..127 -> layer0 chunk c (2 rows each),
// blocks 128..255 -> layer1 chunk c-1. 256 blocks x 512 thr, 1 block/CU.
// Occupancy pinned to 2 waves/EU so the allocator may use 256 VGPRs.
__global__
__attribute__((amdgpu_flat_work_group_size(512, 512), amdgpu_waves_per_eu(1, 2)))
void k_gru_scan_fused(
    const float* __restrict__ gi0, const uint4* __restrict__ wl0,
    const float* __restrict__ bhh0, float* __restrict__ hst0,
    float* __restrict__ h1c,
    const float* __restrict__ gi1, const uint4* __restrict__ wl1,
    const float* __restrict__ bhh1, float* __restrict__ hst1,
    int Tc, int do0, int do1, int init0, int init1)
{
    __shared__ __align__(16) float hbuf[2][2][H_];
    const int blk = blockIdx.x;
    if (blk < 128) {
        if (!do0) return;
        const int b0 = blk * 2;
        gru_scan_core(gi0 + (size_t)b0 * Tc * G3_, wl0, bhh0,
                      hst0 + (size_t)b0 * H_, h1c + (size_t)b0 * Tc * H_,
                      Tc, init0, hbuf);
    } else {
        if (!do1) return;
        const int b0 = (blk - 128) * 2;
        gru_scan_core(gi1 + (size_t)b0 * Tc * G3_, wl1, bhh1,
                      hst1 + (size_t)b0 * H_, nullptr,
                      Tc, init1, hbuf);
    }
}

// ---------------------------------------------------------------------------
__global__ void k_fc(const float* __restrict__ h, const float* __restrict__ Wfc,
                     const float* __restrict__ bfc, float* __restrict__ out)
{
    int idx = blockIdx.x * blockDim.x + threadIdx.x;
    if (idx >= B_ * C_) return;
    int b = idx / C_, c = idx % C_;
    const float* hp = h + (size_t)b * H_;
    const float* wp = Wfc + (size_t)c * H_;
    float s = bfc[c];
#pragma unroll 4
    for (int k = 0; k < H_; k++) s = fmaf(hp[k], wp[k], s);
    out[idx] = s;
}

// ---------------------------------------------------------------------------
extern "C" void kernel_launch(void* const* d_in, const int* in_sizes, int n_in,
                              void* d_out, int out_size, void* d_ws, size_t ws_size,
                              hipStream_t stream)
{
    const float* x    = (const float*)d_in[0];
    const float* Wih0 = (const float*)d_in[1];
    const float* Whh0 = (const float*)d_in[2];
    const float* bih0 = (const float*)d_in[3];
    const float* bhh0 = (const float*)d_in[4];
    const float* Wih1 = (const float*)d_in[5];
    const float* Whh1 = (const float*)d_in[6];
    const float* bih1 = (const float*)d_in[7];
    const float* bhh1 = (const float*)d_in[8];
    const float* Wfc  = (const float*)d_in[9];
    const float* bfc  = (const float*)d_in[10];
    float* out = (float*)d_out;

    const size_t wlBytes = (size_t)48 * 512 * sizeof(uint4);   // 393,216 B

    // ---- largest power-of-two T-chunk that fits ws_size -------------------
    const size_t fixedB = 2 * wlBytes + 2 * (size_t)B_ * H_ * 4 + 8192;
    int Tc = 128, tcShift = 7;
    while (Tc > 1) {
        size_t need = fixedB
                    + 2 * (size_t)B_ * Tc * G3_ * 4    // gi0, gi1 chunks
                    + (size_t)B_ * Tc * H_ * 4;        // h1 chunk
        if (need <= ws_size) break;
        Tc >>= 1; tcShift--;
    }
    const int nChunks = T_ / Tc;

    char* ws = (char*)d_ws;
    size_t off = 0;
    auto alloc = [&](size_t bytes) { char* p = ws + off; off += (bytes + 255) & ~(size_t)255; return p; };
    float* gi0  = (float*)alloc((size_t)B_ * Tc * G3_ * 4);
    float* gi1  = (float*)alloc((size_t)B_ * Tc * G3_ * 4);
    float* h1c  = (float*)alloc((size_t)B_ * Tc * H_ * 4);
    uint4* wl0  = (uint4*)alloc(wlBytes);
    uint4* wl1  = (uint4*)alloc(wlBytes);
    float* hst0 = (float*)alloc((size_t)B_ * H_ * 4);
    float* hst1 = (float*)alloc((size_t)B_ * H_ * 4);

    k_pack_whh<<<48, 512, 0, stream>>>(Whh0, wl0);
    k_pack_whh<<<48, 512, 0, stream>>>(Whh1, wl1);

    const dim3 ggrid(G3_ / 64, (B_ * Tc) / 128);

    // software pipeline: fused launch c runs scan0(c) and scan1(c-1)
    k_gemm_nt_bias<<<ggrid, 256, 0, stream>>>(
        x, (long)T_ * D_, Wih0, bih0, gi0, G3_, D_, tcShift);
    k_gru_scan_fused<<<256, 512, 0, stream>>>(
        gi0, wl0, bhh0, hst0, h1c, gi1, wl1, bhh1, hst1,
        Tc, 1, 0, 1, 0);

    for (int c = 1; c < nChunks; ++c) {
        k_gemm_nt_bias<<<ggrid, 256, 0, stream>>>(
            h1c, (long)Tc * H_, Wih1, bih1, gi1, G3_, H_, tcShift);  // chunk c-1
        k_gemm_nt_bias<<<ggrid, 256, 0, stream>>>(
            x + (size_t)c * Tc * D_, (long)T_ * D_, Wih0, bih0, gi0,
            G3_, D_, tcShift);                                        // chunk c
        k_gru_scan_fused<<<256, 512, 0, stream>>>(
            gi0, wl0, bhh0, hst0, h1c, gi1, wl1, bhh1, hst1,
            Tc, 1, 1, 0, c == 1);
    }

    k_gemm_nt_bias<<<ggrid, 256, 0, stream>>>(
        h1c, (long)Tc * H_, Wih1, bih1, gi1, G3_, H_, tcShift);      // last chunk
    k_gru_scan_fused<<<256, 512, 0, stream>>>(
        gi0, wl0, bhh0, hst0, h1c, gi1, wl1, bhh1, hst1,
        Tc, 0, 1, 0, nChunks == 1);

    k_fc<<<10, 256, 0, stream>>>(hst1, Wfc, bfc, out);
}